// Round 1
// 473.355 us; speedup vs baseline: 1.0036x; 1.0036x over previous
//
#include <hip/hip_runtime.h>

#define NN 512
#define CS 384
#define CZ 128
#define NH 12
#define PROJW 1152
#define FEAT 2112
#define OUTC 384

// workspace float offsets
#define WPROJ 0          // [512][1152]: q 0:192 | k 192:384 | v 384:576 | qp 576:720 | kp 720:864 | vp 864:1152
#define WFEAT 589824     // [512][2112]
#define WOUTP 1671168    // [6][512][384] split-K partials

// ---------------- K1: proj GEMM (512x1152, K=384) + bias + fused point rotation ----------------
__global__ __launch_bounds__(256) void proj_gemm(
    const float* __restrict__ s,
    const float* __restrict__ wq, const float* __restrict__ bq,
    const float* __restrict__ wk, const float* __restrict__ bk,
    const float* __restrict__ wv, const float* __restrict__ bv,
    const float* __restrict__ wqp, const float* __restrict__ bqp,
    const float* __restrict__ wkp, const float* __restrict__ bkp,
    const float* __restrict__ wvp, const float* __restrict__ bvp,
    const float* __restrict__ rot, const float* __restrict__ trans,
    float* __restrict__ proj)
{
    __shared__ float As[32*68];
    __shared__ float Ws[32*52];
    int tid = threadIdx.x;
    int gm0 = blockIdx.x * 64;
    int gc0 = blockIdx.y * 48;
    const float *w, *b; int ldw, lc0;
    if      (gc0 < 192) { w = wq;  b = bq;  ldw = 192; lc0 = gc0;       }
    else if (gc0 < 384) { w = wk;  b = bk;  ldw = 192; lc0 = gc0 - 192; }
    else if (gc0 < 576) { w = wv;  b = bv;  ldw = 192; lc0 = gc0 - 384; }
    else if (gc0 < 720) { w = wqp; b = bqp; ldw = 144; lc0 = gc0 - 576; }
    else if (gc0 < 864) { w = wkp; b = bkp; ldw = 144; lc0 = gc0 - 720; }
    else                { w = wvp; b = bvp; ldw = 288; lc0 = gc0 - 864; }

    int mi = tid >> 4, ni = tid & 15;
    int m0 = mi * 4, n0 = ni * 3;
    float acc[4][3] = {};

    for (int k0 = 0; k0 < CS; k0 += 32) {
        for (int idx = tid; idx < 2048; idx += 256) {
            int r = idx >> 5, c = idx & 31;
            As[c*68 + r] = s[(gm0 + r)*CS + k0 + c];
        }
        for (int idx = tid; idx < 1536; idx += 256) {
            int c = idx / 48, j = idx - c*48;
            Ws[c*52 + j] = w[(k0 + c)*ldw + lc0 + j];
        }
        __syncthreads();
        #pragma unroll 8
        for (int kk = 0; kk < 32; ++kk) {
            float4 a = *(const float4*)&As[kk*68 + m0];
            float w0 = Ws[kk*52 + n0], w1 = Ws[kk*52 + n0 + 1], w2 = Ws[kk*52 + n0 + 2];
            acc[0][0] += a.x*w0; acc[0][1] += a.x*w1; acc[0][2] += a.x*w2;
            acc[1][0] += a.y*w0; acc[1][1] += a.y*w1; acc[1][2] += a.y*w2;
            acc[2][0] += a.z*w0; acc[2][1] += a.z*w1; acc[2][2] += a.z*w2;
            acc[3][0] += a.w*w0; acc[3][1] += a.w*w1; acc[3][2] += a.w*w2;
        }
        __syncthreads();
    }

    float b0 = b[lc0 + n0], b1 = b[lc0 + n0 + 1], b2 = b[lc0 + n0 + 2];
    if (gc0 >= 576) {
        #pragma unroll
        for (int i = 0; i < 4; ++i) {
            int gm = gm0 + m0 + i;
            const float* R = rot + gm*9;
            const float* T = trans + gm*3;
            float x = acc[i][0] + b0, y = acc[i][1] + b1, zz = acc[i][2] + b2;
            float gx = R[0]*x + R[1]*y + R[2]*zz + T[0];
            float gy = R[3]*x + R[4]*y + R[5]*zz + T[1];
            float gz = R[6]*x + R[7]*y + R[8]*zz + T[2];
            float* dst = proj + (size_t)gm*PROJW + gc0 + n0;
            dst[0] = gx; dst[1] = gy; dst[2] = gz;
        }
    } else {
        #pragma unroll
        for (int i = 0; i < 4; ++i) {
            float* dst = proj + (size_t)(gm0 + m0 + i)*PROJW + gc0 + n0;
            dst[0] = acc[i][0] + b0; dst[1] = acc[i][1] + b1; dst[2] = acc[i][2] + b2;
        }
    }
}

// ---------------- K2: attention (512 threads/block -> 16 waves/CU) ----------------
__global__ __launch_bounds__(512, 4) void attn_kernel(
    const float* __restrict__ proj, const float* __restrict__ z,
    const int* __restrict__ mask,
    const float* __restrict__ wb, const float* __restrict__ bb,
    const float* __restrict__ rot, const float* __restrict__ trans,
    float* __restrict__ feat)
{
    int n = blockIdx.x, tid = threadIdx.x;
    __shared__ float s_e[NN*16];         // scores -> exp -> normalized w, [m][16] (12 used)
    __shared__ float s_pair[4*NH*128];   // pair partials [mquarter][h][c]
    __shared__ float s_pts[288];
    __shared__ float s_red[32*NH];
    __shared__ float s_M[NH], s_S[NH];

    const float* qrow  = proj + (size_t)n*PROJW;
    const float* qprow = qrow + 576;
    int mn = mask[n];

    // ---- phase A: scores (bias fused), one m-row per thread ----
    {
        int m = tid;
        const float* krow  = proj + (size_t)m*PROJW + 192;
        const float* kprow = proj + (size_t)m*PROJW + 720;
        const float* zrow  = z + ((size_t)n*NN + m) * CZ;
        bool ok = (mn != 0) && (mask[m] != 0);
        float acc[NH];
        #pragma unroll
        for (int h = 0; h < NH; ++h) acc[h] = bb[h];
        #pragma unroll 4
        for (int c4 = 0; c4 < 32; ++c4) {
            float4 zv = *(const float4*)(zrow + c4*4);
            const float* wbp = wb + c4*48;
            #pragma unroll
            for (int e = 0; e < 4; ++e) {
                float zz = (&zv.x)[e];
                #pragma unroll
                for (int h = 0; h < NH; ++h) acc[h] += zz * wbp[e*12 + h];
            }
        }
        float sc[12];
        #pragma unroll
        for (int h = 0; h < NH; ++h) {
            const float* qh = qrow + h*16;
            const float* kh = krow + h*16;
            float dot = 0.f;
            #pragma unroll
            for (int c4 = 0; c4 < 4; ++c4) {
                float4 kv = *(const float4*)(kh + c4*4);
                dot += qh[c4*4+0]*kv.x + qh[c4*4+1]*kv.y + qh[c4*4+2]*kv.z + qh[c4*4+3]*kv.w;
            }
            float pts = 0.f;
            const float* qph = qprow + h*12;
            const float* kph = kprow + h*12;
            #pragma unroll
            for (int j = 0; j < 12; ++j) { float d = qph[j] - kph[j]; pts += d*d; }
            float sv = dot*0.25f - 0.5f*pts + acc[h];
            sc[h] = ok ? sv : -1e30f;
        }
        float* dst = &s_e[m*16];
        *(float4*)(dst)     = make_float4(sc[0], sc[1], sc[2], sc[3]);
        *(float4*)(dst + 4) = make_float4(sc[4], sc[5], sc[6], sc[7]);
        *(float4*)(dst + 8) = make_float4(sc[8], sc[9], sc[10], sc[11]);
    }
    __syncthreads();

    // ---- phase B: max (32 groups of 16 rows) ----
    if (tid < 384) {
        int i = tid / 12, h = tid - i*12;
        float mx = -1e30f;
        for (int mm = i*16; mm < i*16 + 16; ++mm) mx = fmaxf(mx, s_e[mm*16 + h]);
        s_red[tid] = mx;
    }
    __syncthreads();
    if (tid < NH) {
        float mx = -1e30f;
        #pragma unroll
        for (int i = 0; i < 32; ++i) mx = fmaxf(mx, s_red[i*12 + tid]);
        s_M[tid] = mx;
    }
    __syncthreads();
    // ---- phase C: exp in place (one row per thread) ----
    {
        float M[12];
        #pragma unroll
        for (int h = 0; h < NH; ++h) M[h] = s_M[h];
        int m = tid;
        float* row = &s_e[m*16];
        float4 a = *(float4*)row, b4 = *(float4*)(row+4), c4 = *(float4*)(row+8);
        a.x = __expf(a.x - M[0]);  a.y = __expf(a.y - M[1]);
        a.z = __expf(a.z - M[2]);  a.w = __expf(a.w - M[3]);
        b4.x = __expf(b4.x - M[4]); b4.y = __expf(b4.y - M[5]);
        b4.z = __expf(b4.z - M[6]); b4.w = __expf(b4.w - M[7]);
        c4.x = __expf(c4.x - M[8]); c4.y = __expf(c4.y - M[9]);
        c4.z = __expf(c4.z - M[10]); c4.w = __expf(c4.w - M[11]);
        *(float4*)row = a; *(float4*)(row+4) = b4; *(float4*)(row+8) = c4;
    }
    __syncthreads();
    // ---- phase D: sum ----
    if (tid < 384) {
        int i = tid / 12, h = tid - i*12;
        float sm = 0.f;
        for (int mm = i*16; mm < i*16 + 16; ++mm) sm += s_e[mm*16 + h];
        s_red[tid] = sm;
    }
    __syncthreads();
    if (tid < NH) {
        float sm = 0.f;
        #pragma unroll
        for (int i = 0; i < 32; ++i) sm += s_red[i*12 + tid];
        s_S[tid] = sm;
    }
    __syncthreads();
    // ---- phase E: normalize in place (one row per thread) ----
    {
        float iS[12];
        #pragma unroll
        for (int h = 0; h < NH; ++h) iS[h] = 1.0f / s_S[h];
        int m = tid;
        float* row = &s_e[m*16];
        float4 a = *(float4*)row, b4 = *(float4*)(row+4), c4 = *(float4*)(row+8);
        a.x *= iS[0]; a.y *= iS[1]; a.z *= iS[2]; a.w *= iS[3];
        b4.x *= iS[4]; b4.y *= iS[5]; b4.z *= iS[6]; b4.w *= iS[7];
        c4.x *= iS[8]; c4.y *= iS[9]; c4.z *= iS[10]; c4.w *= iS[11];
        *(float4*)row = a; *(float4*)(row+4) = b4; *(float4*)(row+8) = c4;
    }
    __syncthreads();

    float* fout = feat + (size_t)n * FEAT;

    // ---- phase F: v_out scalar (192) + points (288); weights read from s_e (broadcast) ----
    {
        int o = tid;
        if (o < 480) {
            int col, h; bool isPt = (o >= 192);
            if (!isPt) { col = 384 + o;       h = o >> 4; }
            else       { int p = o - 192; col = 864 + p; h = p / 24; }
            const float* pc = proj + col;
            float acc = 0.f;
            for (int mm = 0; mm < NN; mm += 4) {
                float w0 = s_e[(mm+0)*16 + h];
                float w1 = s_e[(mm+1)*16 + h];
                float w2 = s_e[(mm+2)*16 + h];
                float w3 = s_e[(mm+3)*16 + h];
                acc += w0 * pc[(size_t)(mm+0)*PROJW];
                acc += w1 * pc[(size_t)(mm+1)*PROJW];
                acc += w2 * pc[(size_t)(mm+2)*PROJW];
                acc += w3 * pc[(size_t)(mm+3)*PROJW];
            }
            if (!isPt) fout[h*176 + (o & 15)] = acc;
            else       s_pts[o - 192] = acc;
        }
    }
    __syncthreads();
    // ---- phase G: local transform + norms ----
    if (tid < 96) {
        int h = tid >> 3, p = tid & 7;
        const float* R = rot + n*9;
        const float* T = trans + n*3;
        float x  = s_pts[h*24 + p*3]     - T[0];
        float y  = s_pts[h*24 + p*3 + 1] - T[1];
        float zz = s_pts[h*24 + p*3 + 2] - T[2];
        float lx = R[0]*x + R[3]*y + R[6]*zz;
        float ly = R[1]*x + R[4]*y + R[7]*zz;
        float lz = R[2]*x + R[5]*y + R[8]*zz;
        float* fo = fout + h*176 + 16;
        fo[p*3] = lx; fo[p*3+1] = ly; fo[p*3+2] = lz;
        fout[h*176 + 40 + p] = sqrtf(lx*lx + ly*ly + lz*lz);
    }
    // ---- phase H: pair features, m split in 4 quarters of 128 ----
    {
        int c = tid & 127;                       // 0..127
        int mh = tid >> 7;                       // m quarter 0..3
        const float* zb = z + ((size_t)n*NN + mh*128) * CZ + c;
        float pacc[12] = {};
        for (int mm = 0; mm < 128; ++mm) {
            float zv = zb[(size_t)mm * CZ];
            const float* wr = &s_e[(mh*128 + mm)*16];
            float4 a = *(const float4*)wr, b4 = *(const float4*)(wr+4), c4 = *(const float4*)(wr+8);
            pacc[0] += a.x*zv;  pacc[1] += a.y*zv;  pacc[2] += a.z*zv;  pacc[3] += a.w*zv;
            pacc[4] += b4.x*zv; pacc[5] += b4.y*zv; pacc[6] += b4.z*zv; pacc[7] += b4.w*zv;
            pacc[8] += c4.x*zv; pacc[9] += c4.y*zv; pacc[10] += c4.z*zv; pacc[11] += c4.w*zv;
        }
        #pragma unroll
        for (int h = 0; h < NH; ++h) s_pair[(mh*NH + h)*128 + c] = pacc[h];
    }
    __syncthreads();
    {
        int c = tid & 127, jh = tid >> 7;        // jh: h-triple 0..3
        #pragma unroll
        for (int j = 0; j < 3; ++j) {
            int h = jh*3 + j;
            fout[h*176 + 48 + c] = s_pair[h*128 + c] + s_pair[(NH + h)*128 + c]
                                 + s_pair[(2*NH + h)*128 + c] + s_pair[(3*NH + h)*128 + c];
        }
    }
}

// ---------------- K3: out GEMM split-K partials (512x384, K=2112, KC=6 x 352) ----------------
__global__ __launch_bounds__(256) void out_gemm(
    const float* __restrict__ feat, const float* __restrict__ wo,
    float* __restrict__ pout)
{
    __shared__ float As[16*68];
    __shared__ float Ws[16*68];
    int tid = threadIdx.x;
    int gm0 = blockIdx.x * 64, gn0 = blockIdx.y * 64;
    int kc = blockIdx.z;
    int kbase = kc * 352;
    int mi = tid >> 4, ni = tid & 15;
    int m0 = mi * 4, n0 = ni * 4;
    float acc[4][4] = {};

    for (int kt = 0; kt < 22; ++kt) {
        int k0 = kbase + kt*16;
        for (int idx = tid; idx < 1024; idx += 256) {
            int r = idx >> 4, c = idx & 15;
            As[c*68 + r] = feat[(size_t)(gm0 + r)*FEAT + k0 + c];
        }
        for (int idx = tid; idx < 1024; idx += 256) {
            int r = idx >> 6, c = idx & 63;
            Ws[r*68 + c] = wo[(size_t)(k0 + r)*OUTC + gn0 + c];
        }
        __syncthreads();
        #pragma unroll 8
        for (int kk = 0; kk < 16; ++kk) {
            float4 a = *(const float4*)&As[kk*68 + m0];
            float4 w = *(const float4*)&Ws[kk*68 + n0];
            acc[0][0] += a.x*w.x; acc[0][1] += a.x*w.y; acc[0][2] += a.x*w.z; acc[0][3] += a.x*w.w;
            acc[1][0] += a.y*w.x; acc[1][1] += a.y*w.y; acc[1][2] += a.y*w.z; acc[1][3] += a.y*w.w;
            acc[2][0] += a.z*w.x; acc[2][1] += a.z*w.y; acc[2][2] += a.z*w.z; acc[2][3] += a.z*w.w;
            acc[3][0] += a.w*w.x; acc[3][1] += a.w*w.y; acc[3][2] += a.w*w.z; acc[3][3] += a.w*w.w;
        }
        __syncthreads();
    }
    float* pb = pout + (size_t)kc * (NN*OUTC);
    #pragma unroll
    for (int i = 0; i < 4; ++i)
        *(float4*)&pb[(size_t)(gm0 + m0 + i)*OUTC + gn0 + n0] =
            make_float4(acc[i][0], acc[i][1], acc[i][2], acc[i][3]);
}

// ---------------- K4: reduce partials + bias ----------------
__global__ __launch_bounds__(256) void out_reduce(
    const float* __restrict__ pout, const float* __restrict__ bo,
    float* __restrict__ out)
{
    int idx4 = blockIdx.x * 256 + threadIdx.x;   // 49152 float4s
    int col4 = idx4 % 96;
    const float4* b4 = (const float4*)bo;
    float4 acc = b4[col4];
    #pragma unroll
    for (int kc = 0; kc < 6; ++kc) {
        float4 p = ((const float4*)(pout + (size_t)kc*(NN*OUTC)))[idx4];
        acc.x += p.x; acc.y += p.y; acc.z += p.z; acc.w += p.w;
    }
    ((float4*)out)[idx4] = acc;
}

extern "C" void kernel_launch(void* const* d_in, const int* in_sizes, int n_in,
                              void* d_out, int out_size, void* d_ws, size_t ws_size,
                              hipStream_t stream) {
    (void)in_sizes; (void)n_in; (void)out_size; (void)ws_size;
    const float* s     = (const float*)d_in[0];
    const float* z     = (const float*)d_in[1];
    const float* trans = (const float*)d_in[2];
    const float* rot   = (const float*)d_in[3];
    const int*   mask  = (const int*)d_in[4];
    const float* wq    = (const float*)d_in[5];
    const float* bq    = (const float*)d_in[6];
    const float* wk    = (const float*)d_in[7];
    const float* bk    = (const float*)d_in[8];
    const float* wv    = (const float*)d_in[9];
    const float* bv    = (const float*)d_in[10];
    const float* wqp   = (const float*)d_in[11];
    const float* bqp   = (const float*)d_in[12];
    const float* wkp   = (const float*)d_in[13];
    const float* bkp   = (const float*)d_in[14];
    const float* wvp   = (const float*)d_in[15];
    const float* bvp   = (const float*)d_in[16];
    const float* wb    = (const float*)d_in[17];
    const float* bb    = (const float*)d_in[18];
    const float* wo    = (const float*)d_in[19];
    const float* bo    = (const float*)d_in[20];
    float* ws  = (float*)d_ws;
    float* out = (float*)d_out;

    proj_gemm<<<dim3(8, 24), 256, 0, stream>>>(
        s, wq, bq, wk, bk, wv, bv, wqp, bqp, wkp, bkp, wvp, bvp, rot, trans, ws + WPROJ);
    attn_kernel<<<NN, 512, 0, stream>>>(ws + WPROJ, z, mask, wb, bb, rot, trans, ws + WFEAT);
    out_gemm<<<dim3(8, 6, 6), 256, 0, stream>>>(ws + WFEAT, wo, ws + WOUTP);
    out_reduce<<<192, 256, 0, stream>>>(ws + WOUTP, bo, out);
}

// Round 2
// 461.814 us; speedup vs baseline: 1.0287x; 1.0250x over previous
//
#include <hip/hip_runtime.h>

#define NN 512
#define CS 384
#define CZ 128
#define NH 12
#define PROJW 1152
#define FEAT 2112
#define OUTC 384
#define SEP 20          // s_e row stride (floats): conflict-free float4 row ops

// workspace float offsets
#define WPROJ 0          // [512][1152]: q 0:192 | k 192:384 | v 384:576 | qp 576:720 | kp 720:864 | vp 864:1152
#define WFEAT 589824     // [512][2112]
#define WOUTP 1671168    // [6][512][384] split-K partials
#define WKT   2850816    // [336][512]: kT rows 0:192 = k cols, 192:336 = rotated kp cols

// ---------------- K1: proj GEMM (512x1152, K=384) + bias + fused point rotation + kT ----------------
__global__ __launch_bounds__(256) void proj_gemm(
    const float* __restrict__ s,
    const float* __restrict__ wq, const float* __restrict__ bq,
    const float* __restrict__ wk, const float* __restrict__ bk,
    const float* __restrict__ wv, const float* __restrict__ bv,
    const float* __restrict__ wqp, const float* __restrict__ bqp,
    const float* __restrict__ wkp, const float* __restrict__ bkp,
    const float* __restrict__ wvp, const float* __restrict__ bvp,
    const float* __restrict__ rot, const float* __restrict__ trans,
    float* __restrict__ proj, float* __restrict__ kT)
{
    __shared__ float As[32*68];
    __shared__ float Ws[32*52];
    int tid = threadIdx.x;
    int gm0 = blockIdx.x * 64;
    int gc0 = blockIdx.y * 48;
    const float *w, *b; int ldw, lc0;
    if      (gc0 < 192) { w = wq;  b = bq;  ldw = 192; lc0 = gc0;       }
    else if (gc0 < 384) { w = wk;  b = bk;  ldw = 192; lc0 = gc0 - 192; }
    else if (gc0 < 576) { w = wv;  b = bv;  ldw = 192; lc0 = gc0 - 384; }
    else if (gc0 < 720) { w = wqp; b = bqp; ldw = 144; lc0 = gc0 - 576; }
    else if (gc0 < 864) { w = wkp; b = bkp; ldw = 144; lc0 = gc0 - 720; }
    else                { w = wvp; b = bvp; ldw = 288; lc0 = gc0 - 864; }

    int mi = tid >> 4, ni = tid & 15;
    int m0 = mi * 4, n0 = ni * 3;
    float acc[4][3] = {};

    for (int k0 = 0; k0 < CS; k0 += 32) {
        for (int idx = tid; idx < 2048; idx += 256) {
            int r = idx >> 5, c = idx & 31;
            As[c*68 + r] = s[(gm0 + r)*CS + k0 + c];
        }
        for (int idx = tid; idx < 1536; idx += 256) {
            int c = idx / 48, j = idx - c*48;
            Ws[c*52 + j] = w[(k0 + c)*ldw + lc0 + j];
        }
        __syncthreads();
        #pragma unroll 8
        for (int kk = 0; kk < 32; ++kk) {
            float4 a = *(const float4*)&As[kk*68 + m0];
            float w0 = Ws[kk*52 + n0], w1 = Ws[kk*52 + n0 + 1], w2 = Ws[kk*52 + n0 + 2];
            acc[0][0] += a.x*w0; acc[0][1] += a.x*w1; acc[0][2] += a.x*w2;
            acc[1][0] += a.y*w0; acc[1][1] += a.y*w1; acc[1][2] += a.y*w2;
            acc[2][0] += a.z*w0; acc[2][1] += a.z*w1; acc[2][2] += a.z*w2;
            acc[3][0] += a.w*w0; acc[3][1] += a.w*w1; acc[3][2] += a.w*w2;
        }
        __syncthreads();
    }

    float b0 = b[lc0 + n0], b1 = b[lc0 + n0 + 1], b2 = b[lc0 + n0 + 2];
    if (gc0 >= 576) {
        #pragma unroll
        for (int i = 0; i < 4; ++i) {
            int gm = gm0 + m0 + i;
            const float* R = rot + gm*9;
            const float* T = trans + gm*3;
            float x = acc[i][0] + b0, y = acc[i][1] + b1, zz = acc[i][2] + b2;
            float gx = R[0]*x + R[1]*y + R[2]*zz + T[0];
            float gy = R[3]*x + R[4]*y + R[5]*zz + T[1];
            float gz = R[6]*x + R[7]*y + R[8]*zz + T[2];
            float* dst = proj + (size_t)gm*PROJW + gc0 + n0;
            dst[0] = gx; dst[1] = gy; dst[2] = gz;
            if (gc0 >= 720 && gc0 < 864) {        // rotated kp -> kT rows 192..335
                int c = 192 + (gc0 - 720) + n0;
                kT[(size_t)(c+0)*NN + gm] = gx;
                kT[(size_t)(c+1)*NN + gm] = gy;
                kT[(size_t)(c+2)*NN + gm] = gz;
            }
        }
    } else {
        #pragma unroll
        for (int i = 0; i < 4; ++i) {
            int gm = gm0 + m0 + i;
            float v0 = acc[i][0] + b0, v1 = acc[i][1] + b1, v2 = acc[i][2] + b2;
            float* dst = proj + (size_t)gm*PROJW + gc0 + n0;
            dst[0] = v0; dst[1] = v1; dst[2] = v2;
            if (gc0 >= 192 && gc0 < 384) {        // k -> kT rows 0..191
                int c = gc0 - 192 + n0;
                kT[(size_t)(c+0)*NN + gm] = v0;
                kT[(size_t)(c+1)*NN + gm] = v1;
                kT[(size_t)(c+2)*NN + gm] = v2;
            }
        }
    }
}

// ---------------- K2: attention ----------------
__global__ __launch_bounds__(512, 4) void attn_kernel(
    const float* __restrict__ proj, const float* __restrict__ kT,
    const float* __restrict__ z,
    const int* __restrict__ mask,
    const float* __restrict__ wb, const float* __restrict__ bb,
    const float* __restrict__ rot, const float* __restrict__ trans,
    float* __restrict__ feat)
{
    int n = blockIdx.x, tid = threadIdx.x;
    __shared__ float s_e[NN*SEP];        // bias -> scores -> exp -> normalized w, [m][SEP] (12 used)
    __shared__ float s_u[8192];          // union: zl [64][128] swizzled | s_pair [4][12][128]
    __shared__ float s_pts[288];
    __shared__ float s_red[384];
    __shared__ float s_M[NH], s_S[NH];

    const float* qrow  = proj + (size_t)n*PROJW;
    const float* qprow = qrow + 576;
    int mn = mask[n];

    // ---- phase A0: bias = z @ wb + bb, computed from LDS-staged coalesced z tiles ----
    {
        const float* zn = z + (size_t)n*NN*CZ;
        float4 stg[4], stg2[4];
        #pragma unroll
        for (int k = 0; k < 4; ++k) stg[k] = ((const float4*)zn)[tid + k*512];
        for (int t = 0; t < 8; ++t) {
            // write staged tile to zl (XOR-swizzled: conflict-free b128 r/w)
            #pragma unroll
            for (int k = 0; k < 4; ++k) {
                int i = tid + k*512;
                int r = i >> 5, c4 = i & 31;
                *(float4*)&s_u[r*128 + ((c4 ^ (r & 7)) << 2)] = stg[k];
            }
            // prefetch next tile (hides HBM latency under compute)
            if (t < 7) {
                const float* znn = zn + (size_t)(t+1)*64*CZ;
                #pragma unroll
                for (int k = 0; k < 4; ++k) stg2[k] = ((const float4*)znn)[tid + k*512];
            }
            __syncthreads();
            if (tid < 256) {
                int ml = tid & 63, hg = tid >> 6;      // 4 groups x 3 heads
                int h0 = __builtin_amdgcn_readfirstlane(hg * 3);
                const float* wb0 = wb + h0;            // wave-uniform -> s_loads
                float a0 = bb[h0], a1 = bb[h0+1], a2 = bb[h0+2];
                #pragma unroll 8
                for (int c4 = 0; c4 < 32; ++c4) {
                    float4 v = *(const float4*)&s_u[ml*128 + ((c4 ^ (ml & 7)) << 2)];
                    int cb = c4*4;
                    a0 += v.x*wb0[(cb+0)*12]   + v.y*wb0[(cb+1)*12]   + v.z*wb0[(cb+2)*12]   + v.w*wb0[(cb+3)*12];
                    a1 += v.x*wb0[(cb+0)*12+1] + v.y*wb0[(cb+1)*12+1] + v.z*wb0[(cb+2)*12+1] + v.w*wb0[(cb+3)*12+1];
                    a2 += v.x*wb0[(cb+0)*12+2] + v.y*wb0[(cb+1)*12+2] + v.z*wb0[(cb+2)*12+2] + v.w*wb0[(cb+3)*12+2];
                }
                float* se = &s_e[(t*64 + ml)*SEP + h0];
                se[0] = a0; se[1] = a1; se[2] = a2;
            }
            __syncthreads();
            #pragma unroll
            for (int k = 0; k < 4; ++k) stg[k] = stg2[k];
        }
    }

    // ---- phase A: scores via transposed k/kp (lane-coalesced loads) ----
    {
        int m = tid;
        bool ok = (mn != 0) && (mask[m] != 0);
        float sc[12];
        #pragma unroll 2
        for (int h = 0; h < NH; ++h) {
            const float* qh  = qrow + h*16;
            const float* kTh = kT + (size_t)(h*16)*NN + m;
            float dot = 0.f;
            #pragma unroll
            for (int cc = 0; cc < 16; ++cc) dot += qh[cc] * kTh[(size_t)cc*NN];
            const float* qph  = qprow + h*12;
            const float* kpTh = kT + (size_t)(192 + h*12)*NN + m;
            float pts = 0.f;
            #pragma unroll
            for (int j = 0; j < 12; ++j) { float d = qph[j] - kpTh[(size_t)j*NN]; pts += d*d; }
            sc[h] = dot*0.25f - 0.5f*pts;
        }
        float* row = &s_e[m*SEP];
        #pragma unroll
        for (int h = 0; h < NH; ++h) {
            float v = sc[h] + row[h];
            row[h] = ok ? v : -1e30f;
        }
    }
    __syncthreads();

    // ---- phase B: max ----
    if (tid < 384) {
        int i = tid / 12, h = tid - i*12;
        float mx = -1e30f;
        for (int mm = i*16; mm < i*16 + 16; ++mm) mx = fmaxf(mx, s_e[mm*SEP + h]);
        s_red[tid] = mx;
    }
    __syncthreads();
    if (tid < NH) {
        float mx = -1e30f;
        #pragma unroll
        for (int i = 0; i < 32; ++i) mx = fmaxf(mx, s_red[i*12 + tid]);
        s_M[tid] = mx;
    }
    __syncthreads();
    // ---- phase C: exp in place ----
    {
        float M[12];
        #pragma unroll
        for (int h = 0; h < NH; ++h) M[h] = s_M[h];
        float* row = &s_e[tid*SEP];
        float4 a = *(float4*)row, b4 = *(float4*)(row+4), c4 = *(float4*)(row+8);
        a.x = __expf(a.x - M[0]);  a.y = __expf(a.y - M[1]);
        a.z = __expf(a.z - M[2]);  a.w = __expf(a.w - M[3]);
        b4.x = __expf(b4.x - M[4]); b4.y = __expf(b4.y - M[5]);
        b4.z = __expf(b4.z - M[6]); b4.w = __expf(b4.w - M[7]);
        c4.x = __expf(c4.x - M[8]); c4.y = __expf(c4.y - M[9]);
        c4.z = __expf(c4.z - M[10]); c4.w = __expf(c4.w - M[11]);
        *(float4*)row = a; *(float4*)(row+4) = b4; *(float4*)(row+8) = c4;
    }
    __syncthreads();
    // ---- phase D: sum ----
    if (tid < 384) {
        int i = tid / 12, h = tid - i*12;
        float sm = 0.f;
        for (int mm = i*16; mm < i*16 + 16; ++mm) sm += s_e[mm*SEP + h];
        s_red[tid] = sm;
    }
    __syncthreads();
    if (tid < NH) {
        float sm = 0.f;
        #pragma unroll
        for (int i = 0; i < 32; ++i) sm += s_red[i*12 + tid];
        s_S[tid] = sm;
    }
    __syncthreads();
    // ---- phase E: normalize in place ----
    {
        float iS[12];
        #pragma unroll
        for (int h = 0; h < NH; ++h) iS[h] = 1.0f / s_S[h];
        float* row = &s_e[tid*SEP];
        float4 a = *(float4*)row, b4 = *(float4*)(row+4), c4 = *(float4*)(row+8);
        a.x *= iS[0]; a.y *= iS[1]; a.z *= iS[2]; a.w *= iS[3];
        b4.x *= iS[4]; b4.y *= iS[5]; b4.z *= iS[6]; b4.w *= iS[7];
        c4.x *= iS[8]; c4.y *= iS[9]; c4.z *= iS[10]; c4.w *= iS[11];
        *(float4*)row = a; *(float4*)(row+4) = b4; *(float4*)(row+8) = c4;
    }
    __syncthreads();

    float* fout = feat + (size_t)n * FEAT;

    // ---- phase F: v_out scalar (192) + points (288), software-pipelined column loads ----
    {
        int o = tid;
        if (o < 480) {
            int col, h; bool isPt = (o >= 192);
            if (!isPt) { col = 384 + o;       h = o >> 4; }
            else       { int p = o - 192; col = 864 + p; h = p / 24; }
            const float* pc = proj + col;
            float acc = 0.f;
            float pv[16], nv[16];
            #pragma unroll
            for (int j = 0; j < 16; ++j) pv[j] = pc[(size_t)j*PROJW];
            for (int mm = 0; mm < NN; mm += 16) {
                if (mm + 16 < NN) {
                    #pragma unroll
                    for (int j = 0; j < 16; ++j) nv[j] = pc[(size_t)(mm+16+j)*PROJW];
                }
                #pragma unroll
                for (int j = 0; j < 16; ++j) acc += s_e[(mm+j)*SEP + h] * pv[j];
                #pragma unroll
                for (int j = 0; j < 16; ++j) pv[j] = nv[j];
            }
            if (!isPt) fout[h*176 + (o & 15)] = acc;
            else       s_pts[o - 192] = acc;
        }
    }
    __syncthreads();
    // ---- phase G: local transform + norms ----
    if (tid < 96) {
        int h = tid >> 3, p = tid & 7;
        const float* R = rot + n*9;
        const float* T = trans + n*3;
        float x  = s_pts[h*24 + p*3]     - T[0];
        float y  = s_pts[h*24 + p*3 + 1] - T[1];
        float zz = s_pts[h*24 + p*3 + 2] - T[2];
        float lx = R[0]*x + R[3]*y + R[6]*zz;
        float ly = R[1]*x + R[4]*y + R[7]*zz;
        float lz = R[2]*x + R[5]*y + R[8]*zz;
        float* fo = fout + h*176 + 16;
        fo[p*3] = lx; fo[p*3+1] = ly; fo[p*3+2] = lz;
        fout[h*176 + 40 + p] = sqrtf(lx*lx + ly*ly + lz*lz);
    }
    // ---- phase H: pair features, m split in 4 quarters of 128, software-pipelined z loads ----
    {
        int c = tid & 127;                       // 0..127
        int mh = tid >> 7;                       // m quarter 0..3
        const float* zb = z + ((size_t)n*NN + mh*128) * CZ + c;
        float pacc[12] = {};
        float zv[16], zn2[16];
        #pragma unroll
        for (int j = 0; j < 16; ++j) zv[j] = zb[(size_t)j*CZ];
        for (int mm = 0; mm < 128; mm += 16) {
            if (mm + 16 < 128) {
                #pragma unroll
                for (int j = 0; j < 16; ++j) zn2[j] = zb[(size_t)(mm+16+j)*CZ];
            }
            #pragma unroll
            for (int j = 0; j < 16; ++j) {
                const float* wr = &s_e[(mh*128 + mm + j)*SEP];
                float4 a = *(const float4*)wr, b4 = *(const float4*)(wr+4), c4v = *(const float4*)(wr+8);
                float zz = zv[j];
                pacc[0] += a.x*zz;  pacc[1] += a.y*zz;  pacc[2] += a.z*zz;  pacc[3] += a.w*zz;
                pacc[4] += b4.x*zz; pacc[5] += b4.y*zz; pacc[6] += b4.z*zz; pacc[7] += b4.w*zz;
                pacc[8] += c4v.x*zz; pacc[9] += c4v.y*zz; pacc[10] += c4v.z*zz; pacc[11] += c4v.w*zz;
            }
            #pragma unroll
            for (int j = 0; j < 16; ++j) zv[j] = zn2[j];
        }
        #pragma unroll
        for (int h = 0; h < NH; ++h) s_u[(mh*NH + h)*128 + c] = pacc[h];
    }
    __syncthreads();
    {
        int c = tid & 127, jh = tid >> 7;        // jh: h-triple 0..3
        #pragma unroll
        for (int j = 0; j < 3; ++j) {
            int h = jh*3 + j;
            fout[h*176 + 48 + c] = s_u[h*128 + c] + s_u[(NH + h)*128 + c]
                                 + s_u[(2*NH + h)*128 + c] + s_u[(3*NH + h)*128 + c];
        }
    }
}

// ---------------- K3: out GEMM split-K partials (512x384, K=2112, KC=6 x 352) ----------------
__global__ __launch_bounds__(256) void out_gemm(
    const float* __restrict__ feat, const float* __restrict__ wo,
    float* __restrict__ pout)
{
    __shared__ float As[16*68];
    __shared__ float Ws[16*68];
    int tid = threadIdx.x;
    int gm0 = blockIdx.x * 64, gn0 = blockIdx.y * 64;
    int kc = blockIdx.z;
    int kbase = kc * 352;
    int mi = tid >> 4, ni = tid & 15;
    int m0 = mi * 4, n0 = ni * 4;
    float acc[4][4] = {};

    for (int kt = 0; kt < 22; ++kt) {
        int k0 = kbase + kt*16;
        for (int idx = tid; idx < 1024; idx += 256) {
            int r = idx >> 4, c = idx & 15;
            As[c*68 + r] = feat[(size_t)(gm0 + r)*FEAT + k0 + c];
        }
        for (int idx = tid; idx < 1024; idx += 256) {
            int r = idx >> 6, c = idx & 63;
            Ws[r*68 + c] = wo[(size_t)(k0 + r)*OUTC + gn0 + c];
        }
        __syncthreads();
        #pragma unroll 8
        for (int kk = 0; kk < 16; ++kk) {
            float4 a = *(const float4*)&As[kk*68 + m0];
            float4 w = *(const float4*)&Ws[kk*68 + n0];
            acc[0][0] += a.x*w.x; acc[0][1] += a.x*w.y; acc[0][2] += a.x*w.z; acc[0][3] += a.x*w.w;
            acc[1][0] += a.y*w.x; acc[1][1] += a.y*w.y; acc[1][2] += a.y*w.z; acc[1][3] += a.y*w.w;
            acc[2][0] += a.z*w.x; acc[2][1] += a.z*w.y; acc[2][2] += a.z*w.z; acc[2][3] += a.z*w.w;
            acc[3][0] += a.w*w.x; acc[3][1] += a.w*w.y; acc[3][2] += a.w*w.z; acc[3][3] += a.w*w.w;
        }
        __syncthreads();
    }
    float* pb = pout + (size_t)kc * (NN*OUTC);
    #pragma unroll
    for (int i = 0; i < 4; ++i)
        *(float4*)&pb[(size_t)(gm0 + m0 + i)*OUTC + gn0 + n0] =
            make_float4(acc[i][0], acc[i][1], acc[i][2], acc[i][3]);
}

// ---------------- K4: reduce partials + bias ----------------
__global__ __launch_bounds__(256) void out_reduce(
    const float* __restrict__ pout, const float* __restrict__ bo,
    float* __restrict__ out)
{
    int idx4 = blockIdx.x * 256 + threadIdx.x;   // 49152 float4s
    int col4 = idx4 % 96;
    const float4* b4 = (const float4*)bo;
    float4 acc = b4[col4];
    #pragma unroll
    for (int kc = 0; kc < 6; ++kc) {
        float4 p = ((const float4*)(pout + (size_t)kc*(NN*OUTC)))[idx4];
        acc.x += p.x; acc.y += p.y; acc.z += p.z; acc.w += p.w;
    }
    ((float4*)out)[idx4] = acc;
}

extern "C" void kernel_launch(void* const* d_in, const int* in_sizes, int n_in,
                              void* d_out, int out_size, void* d_ws, size_t ws_size,
                              hipStream_t stream) {
    (void)in_sizes; (void)n_in; (void)out_size; (void)ws_size;
    const float* s     = (const float*)d_in[0];
    const float* z     = (const float*)d_in[1];
    const float* trans = (const float*)d_in[2];
    const float* rot   = (const float*)d_in[3];
    const int*   mask  = (const int*)d_in[4];
    const float* wq    = (const float*)d_in[5];
    const float* bq    = (const float*)d_in[6];
    const float* wk    = (const float*)d_in[7];
    const float* bk    = (const float*)d_in[8];
    const float* wv    = (const float*)d_in[9];
    const float* bv    = (const float*)d_in[10];
    const float* wqp   = (const float*)d_in[11];
    const float* bqp   = (const float*)d_in[12];
    const float* wkp   = (const float*)d_in[13];
    const float* bkp   = (const float*)d_in[14];
    const float* wvp   = (const float*)d_in[15];
    const float* bvp   = (const float*)d_in[16];
    const float* wb    = (const float*)d_in[17];
    const float* bb    = (const float*)d_in[18];
    const float* wo    = (const float*)d_in[19];
    const float* bo    = (const float*)d_in[20];
    float* ws  = (float*)d_ws;
    float* out = (float*)d_out;

    proj_gemm<<<dim3(8, 24), 256, 0, stream>>>(
        s, wq, bq, wk, bk, wv, bv, wqp, bqp, wkp, bkp, wvp, bvp, rot, trans,
        ws + WPROJ, ws + WKT);
    attn_kernel<<<NN, 512, 0, stream>>>(ws + WPROJ, ws + WKT, z, mask, wb, bb, rot, trans, ws + WFEAT);
    out_gemm<<<dim3(8, 6, 6), 256, 0, stream>>>(ws + WFEAT, wo, ws + WOUTP);
    out_reduce<<<192, 256, 0, stream>>>(ws + WOUTP, bo, out);
}

// Round 3
// 447.912 us; speedup vs baseline: 1.0606x; 1.0310x over previous
//
#include <hip/hip_runtime.h>

#define NN 512
#define CS 384
#define CZ 128
#define NH 12
#define PROJW 1152
#define FEAT 2112
#define OUTC 384

// workspace float offsets
#define WPROJ 0          // [512][1152]: q 0:192 | k 192:384 | v 384:576 | qp 576:720 | kp 720:864 | vp 864:1152
#define WFEAT 589824     // [512][2112]
#define WW    1671168    // [512*512][12]: bias -> normalized w ; REUSED later as split-K pout
#define WOUTP 1671168    // [6][512][384] split-K partials (written after pair_kernel done reading WW)
#define WKT   4816896    // [336][512]: kT rows 0:192 = k cols, 192:336 = rotated kp cols

// ---------------- K1: proj GEMM (512x1152, K=384) + bias + fused point rotation + kT ----------------
__global__ __launch_bounds__(256) void proj_gemm(
    const float* __restrict__ s,
    const float* __restrict__ wq, const float* __restrict__ bq,
    const float* __restrict__ wk, const float* __restrict__ bk,
    const float* __restrict__ wv, const float* __restrict__ bv,
    const float* __restrict__ wqp, const float* __restrict__ bqp,
    const float* __restrict__ wkp, const float* __restrict__ bkp,
    const float* __restrict__ wvp, const float* __restrict__ bvp,
    const float* __restrict__ rot, const float* __restrict__ trans,
    float* __restrict__ proj, float* __restrict__ kT)
{
    __shared__ float As[32*68];
    __shared__ float Ws[32*52];
    int tid = threadIdx.x;
    int gm0 = blockIdx.x * 64;
    int gc0 = blockIdx.y * 48;
    const float *w, *b; int ldw, lc0;
    if      (gc0 < 192) { w = wq;  b = bq;  ldw = 192; lc0 = gc0;       }
    else if (gc0 < 384) { w = wk;  b = bk;  ldw = 192; lc0 = gc0 - 192; }
    else if (gc0 < 576) { w = wv;  b = bv;  ldw = 192; lc0 = gc0 - 384; }
    else if (gc0 < 720) { w = wqp; b = bqp; ldw = 144; lc0 = gc0 - 576; }
    else if (gc0 < 864) { w = wkp; b = bkp; ldw = 144; lc0 = gc0 - 720; }
    else                { w = wvp; b = bvp; ldw = 288; lc0 = gc0 - 864; }

    int mi = tid >> 4, ni = tid & 15;
    int m0 = mi * 4, n0 = ni * 3;
    float acc[4][3] = {};

    for (int k0 = 0; k0 < CS; k0 += 32) {
        for (int idx = tid; idx < 2048; idx += 256) {
            int r = idx >> 5, c = idx & 31;
            As[c*68 + r] = s[(gm0 + r)*CS + k0 + c];
        }
        for (int idx = tid; idx < 1536; idx += 256) {
            int c = idx / 48, j = idx - c*48;
            Ws[c*52 + j] = w[(k0 + c)*ldw + lc0 + j];
        }
        __syncthreads();
        #pragma unroll 8
        for (int kk = 0; kk < 32; ++kk) {
            float4 a = *(const float4*)&As[kk*68 + m0];
            float w0 = Ws[kk*52 + n0], w1 = Ws[kk*52 + n0 + 1], w2 = Ws[kk*52 + n0 + 2];
            acc[0][0] += a.x*w0; acc[0][1] += a.x*w1; acc[0][2] += a.x*w2;
            acc[1][0] += a.y*w0; acc[1][1] += a.y*w1; acc[1][2] += a.y*w2;
            acc[2][0] += a.z*w0; acc[2][1] += a.z*w1; acc[2][2] += a.z*w2;
            acc[3][0] += a.w*w0; acc[3][1] += a.w*w1; acc[3][2] += a.w*w2;
        }
        __syncthreads();
    }

    float b0 = b[lc0 + n0], b1 = b[lc0 + n0 + 1], b2 = b[lc0 + n0 + 2];
    if (gc0 >= 576) {
        #pragma unroll
        for (int i = 0; i < 4; ++i) {
            int gm = gm0 + m0 + i;
            const float* R = rot + gm*9;
            const float* T = trans + gm*3;
            float x = acc[i][0] + b0, y = acc[i][1] + b1, zz = acc[i][2] + b2;
            float gx = R[0]*x + R[1]*y + R[2]*zz + T[0];
            float gy = R[3]*x + R[4]*y + R[5]*zz + T[1];
            float gz = R[6]*x + R[7]*y + R[8]*zz + T[2];
            float* dst = proj + (size_t)gm*PROJW + gc0 + n0;
            dst[0] = gx; dst[1] = gy; dst[2] = gz;
            if (gc0 >= 720 && gc0 < 864) {        // rotated kp -> kT rows 192..335
                int c = 192 + (gc0 - 720) + n0;
                kT[(size_t)(c+0)*NN + gm] = gx;
                kT[(size_t)(c+1)*NN + gm] = gy;
                kT[(size_t)(c+2)*NN + gm] = gz;
            }
        }
    } else {
        #pragma unroll
        for (int i = 0; i < 4; ++i) {
            int gm = gm0 + m0 + i;
            float v0 = acc[i][0] + b0, v1 = acc[i][1] + b1, v2 = acc[i][2] + b2;
            float* dst = proj + (size_t)gm*PROJW + gc0 + n0;
            dst[0] = v0; dst[1] = v1; dst[2] = v2;
            if (gc0 >= 192 && gc0 < 384) {        // k -> kT rows 0..191
                int c = gc0 - 192 + n0;
                kT[(size_t)(c+0)*NN + gm] = v0;
                kT[(size_t)(c+1)*NN + gm] = v1;
                kT[(size_t)(c+2)*NN + gm] = v2;
            }
        }
    }
}

// ---------------- K2a: bias = z @ wb + bb  -> ww[nm][12]  (4096 blocks, HBM-bound) ----------------
__global__ __launch_bounds__(256) void bias_gemm(
    const float* __restrict__ z,
    const float* __restrict__ wb, const float* __restrict__ bb,
    float* __restrict__ ww)
{
    __shared__ float zl[64*128];     // XOR-swizzled float4 rows
    __shared__ float sb[64*12];
    int tid = threadIdx.x;
    size_t r0 = (size_t)blockIdx.x * 64;          // global nm row base

    const float4* src = (const float4*)(z + r0*CZ);
    float4 v[8];
    #pragma unroll
    for (int k = 0; k < 8; ++k) v[k] = src[tid + k*256];
    #pragma unroll
    for (int k = 0; k < 8; ++k) {
        int i = tid + k*256;
        int r = i >> 5, c4 = i & 31;
        *(float4*)&zl[r*128 + ((c4 ^ (r & 7)) << 2)] = v[k];
    }
    __syncthreads();

    int r = tid & 63, hg = tid >> 6;              // wave-uniform hg
    int h0 = __builtin_amdgcn_readfirstlane(hg * 3);
    const float* wbp = wb + h0;
    float a0 = bb[h0], a1 = bb[h0+1], a2 = bb[h0+2];
    #pragma unroll 8
    for (int c4 = 0; c4 < 32; ++c4) {
        float4 zv = *(const float4*)&zl[r*128 + ((c4 ^ (r & 7)) << 2)];
        int cb = c4*4;
        a0 += zv.x*wbp[cb*12]     + zv.y*wbp[(cb+1)*12]     + zv.z*wbp[(cb+2)*12]     + zv.w*wbp[(cb+3)*12];
        a1 += zv.x*wbp[cb*12 + 1] + zv.y*wbp[(cb+1)*12 + 1] + zv.z*wbp[(cb+2)*12 + 1] + zv.w*wbp[(cb+3)*12 + 1];
        a2 += zv.x*wbp[cb*12 + 2] + zv.y*wbp[(cb+1)*12 + 2] + zv.z*wbp[(cb+2)*12 + 2] + zv.w*wbp[(cb+3)*12 + 2];
    }
    float* sd = &sb[r*12 + h0];
    sd[0] = a0; sd[1] = a1; sd[2] = a2;
    __syncthreads();
    if (tid < 192) ((float4*)(ww + r0*12))[tid] = ((const float4*)sb)[tid];
}

// ---------------- K2b: scores (kT) + softmax + write w + v_out scalar/points/norms ----------------
__global__ __launch_bounds__(512, 4) void score_kernel(
    const float* __restrict__ proj, const float* __restrict__ kT,
    float* __restrict__ ww,                      // bias in, normalized w out
    const int* __restrict__ mask,
    const float* __restrict__ rot, const float* __restrict__ trans,
    float* __restrict__ feat)
{
    int n = blockIdx.x, tid = threadIdx.x;
    __shared__ float s_e[NN*12];     // bias -> scores -> exp -> w, [m][12]
    __shared__ float s_q[336];       // q (192) + rotated qp (144)
    __shared__ float s_pts[288];
    __shared__ float s_red[384];
    __shared__ float s_M[NH], s_S[NH];

    // load bias rows + q row
    {
        const float4* src = (const float4*)(ww + (size_t)n*NN*12);
        float4* dst = (float4*)s_e;
        #pragma unroll
        for (int k = 0; k < 3; ++k) dst[tid + k*512] = src[tid + k*512];
    }
    if (tid < 336) s_q[tid] = proj[(size_t)n*PROJW + (tid < 192 ? tid : 384 + tid)];
    int mn = mask[n];
    __syncthreads();

    // scores via transposed k/kp (lane-coalesced kT loads)
    {
        int m = tid;
        bool ok = (mn != 0) && (mask[m] != 0);
        float sc[12];
        #pragma unroll 2
        for (int h = 0; h < NH; ++h) {
            const float* qh  = &s_q[h*16];
            const float* kTh = kT + (size_t)(h*16)*NN + m;
            float dot = 0.f;
            #pragma unroll
            for (int cc = 0; cc < 16; ++cc) dot += qh[cc] * kTh[(size_t)cc*NN];
            const float* qph  = &s_q[192 + h*12];
            const float* kpTh = kT + (size_t)(192 + h*12)*NN + m;
            float pts = 0.f;
            #pragma unroll
            for (int j = 0; j < 12; ++j) { float d = qph[j] - kpTh[(size_t)j*NN]; pts += d*d; }
            sc[h] = dot*0.25f - 0.5f*pts;
        }
        float* row = &s_e[m*12];
        #pragma unroll
        for (int h = 0; h < NH; ++h) {
            float v = sc[h] + row[h];
            row[h] = ok ? v : -1e30f;
        }
    }
    __syncthreads();
    // max
    if (tid < 384) {
        int i = tid / 12, h = tid - i*12;
        float mx = -1e30f;
        for (int mm = i*16; mm < i*16 + 16; ++mm) mx = fmaxf(mx, s_e[mm*12 + h]);
        s_red[tid] = mx;
    }
    __syncthreads();
    if (tid < NH) {
        float mx = -1e30f;
        #pragma unroll
        for (int i = 0; i < 32; ++i) mx = fmaxf(mx, s_red[i*12 + tid]);
        s_M[tid] = mx;
    }
    __syncthreads();
    // exp in place
    {
        float M[12];
        #pragma unroll
        for (int h = 0; h < NH; ++h) M[h] = s_M[h];
        float* row = &s_e[tid*12];
        float4 a = *(float4*)row, b4 = *(float4*)(row+4), c4 = *(float4*)(row+8);
        a.x = __expf(a.x - M[0]);  a.y = __expf(a.y - M[1]);
        a.z = __expf(a.z - M[2]);  a.w = __expf(a.w - M[3]);
        b4.x = __expf(b4.x - M[4]); b4.y = __expf(b4.y - M[5]);
        b4.z = __expf(b4.z - M[6]); b4.w = __expf(b4.w - M[7]);
        c4.x = __expf(c4.x - M[8]); c4.y = __expf(c4.y - M[9]);
        c4.z = __expf(c4.z - M[10]); c4.w = __expf(c4.w - M[11]);
        *(float4*)row = a; *(float4*)(row+4) = b4; *(float4*)(row+8) = c4;
    }
    __syncthreads();
    // sum
    if (tid < 384) {
        int i = tid / 12, h = tid - i*12;
        float sm = 0.f;
        for (int mm = i*16; mm < i*16 + 16; ++mm) sm += s_e[mm*12 + h];
        s_red[tid] = sm;
    }
    __syncthreads();
    if (tid < NH) {
        float sm = 0.f;
        #pragma unroll
        for (int i = 0; i < 32; ++i) sm += s_red[i*12 + tid];
        s_S[tid] = sm;
    }
    __syncthreads();
    // normalize in place
    {
        float iS[12];
        #pragma unroll
        for (int h = 0; h < NH; ++h) iS[h] = 1.0f / s_S[h];
        float* row = &s_e[tid*12];
        float4 a = *(float4*)row, b4 = *(float4*)(row+4), c4 = *(float4*)(row+8);
        a.x *= iS[0]; a.y *= iS[1]; a.z *= iS[2]; a.w *= iS[3];
        b4.x *= iS[4]; b4.y *= iS[5]; b4.z *= iS[6]; b4.w *= iS[7];
        c4.x *= iS[8]; c4.y *= iS[9]; c4.z *= iS[10]; c4.w *= iS[11];
        *(float4*)row = a; *(float4*)(row+4) = b4; *(float4*)(row+8) = c4;
    }
    __syncthreads();
    // write normalized w back for pair_kernel
    {
        float4* dst = (float4*)(ww + (size_t)n*NN*12);
        const float4* src = (const float4*)s_e;
        #pragma unroll
        for (int k = 0; k < 3; ++k) dst[tid + k*512] = src[tid + k*512];
    }

    float* fout = feat + (size_t)n * FEAT;

    // v_out scalar (192) + points (288); plain loop, compiler-scheduled, 2 accumulators
    {
        int o = tid;
        if (o < 480) {
            int col, h; bool isPt = (o >= 192);
            if (!isPt) { col = 384 + o;       h = o >> 4; }
            else       { int p = o - 192; col = 864 + p; h = p / 24; }
            const float* pc = proj + col;
            float acc0 = 0.f, acc1 = 0.f;
            #pragma unroll 8
            for (int mm = 0; mm < NN; mm += 2) {
                acc0 += s_e[(mm  )*12 + h] * pc[(size_t)(mm  )*PROJW];
                acc1 += s_e[(mm+1)*12 + h] * pc[(size_t)(mm+1)*PROJW];
            }
            float acc = acc0 + acc1;
            if (!isPt) fout[h*176 + (o & 15)] = acc;
            else       s_pts[o - 192] = acc;
        }
    }
    __syncthreads();
    // local transform + norms
    if (tid < 96) {
        int h = tid >> 3, p = tid & 7;
        const float* R = rot + n*9;
        const float* T = trans + n*3;
        float x  = s_pts[h*24 + p*3]     - T[0];
        float y  = s_pts[h*24 + p*3 + 1] - T[1];
        float zz = s_pts[h*24 + p*3 + 2] - T[2];
        float lx = R[0]*x + R[3]*y + R[6]*zz;
        float ly = R[1]*x + R[4]*y + R[7]*zz;
        float lz = R[2]*x + R[5]*y + R[8]*zz;
        float* fo = fout + h*176 + 16;
        fo[p*3] = lx; fo[p*3+1] = ly; fo[p*3+2] = lz;
        fout[h*176 + 40 + p] = sqrtf(lx*lx + ly*ly + lz*lz);
    }
}

// ---------------- K2c: pair features = w . z  (per n, z re-read from L3) ----------------
__global__ __launch_bounds__(512, 4) void pair_kernel(
    const float* __restrict__ ww, const float* __restrict__ z,
    float* __restrict__ feat)
{
    int n = blockIdx.x, tid = threadIdx.x;
    __shared__ float s_w[NN*12];
    __shared__ float s_p[4*NH*128];
    {
        const float4* src = (const float4*)(ww + (size_t)n*NN*12);
        float4* dst = (float4*)s_w;
        #pragma unroll
        for (int k = 0; k < 3; ++k) dst[tid + k*512] = src[tid + k*512];
    }
    __syncthreads();
    int c = tid & 127, mh = tid >> 7;             // c column, m quarter
    const float* zb = z + ((size_t)n*NN + mh*128) * CZ + c;
    float pacc[12] = {};
    #pragma unroll 4
    for (int mm = 0; mm < 128; ++mm) {
        float zv = zb[(size_t)mm * CZ];
        const float* wr = &s_w[(mh*128 + mm)*12];           // broadcast across lanes
        float4 a = *(const float4*)wr, b4 = *(const float4*)(wr+4), c4 = *(const float4*)(wr+8);
        pacc[0] += a.x*zv;  pacc[1] += a.y*zv;  pacc[2] += a.z*zv;  pacc[3] += a.w*zv;
        pacc[4] += b4.x*zv; pacc[5] += b4.y*zv; pacc[6] += b4.z*zv; pacc[7] += b4.w*zv;
        pacc[8] += c4.x*zv; pacc[9] += c4.y*zv; pacc[10] += c4.z*zv; pacc[11] += c4.w*zv;
    }
    #pragma unroll
    for (int h = 0; h < NH; ++h) s_p[(mh*NH + h)*128 + c] = pacc[h];
    __syncthreads();
    {
        float* fout = feat + (size_t)n * FEAT;
        int cc = tid & 127, jh = tid >> 7;
        #pragma unroll
        for (int j = 0; j < 3; ++j) {
            int h = jh*3 + j;
            fout[h*176 + 48 + cc] = s_p[h*128 + cc] + s_p[(NH + h)*128 + cc]
                                  + s_p[(2*NH + h)*128 + cc] + s_p[(3*NH + h)*128 + cc];
        }
    }
}

// ---------------- K3: out GEMM split-K partials (512x384, K=2112, KC=6 x 352) ----------------
__global__ __launch_bounds__(256) void out_gemm(
    const float* __restrict__ feat, const float* __restrict__ wo,
    float* __restrict__ pout)
{
    __shared__ float As[16*68];
    __shared__ float Ws[16*68];
    int tid = threadIdx.x;
    int gm0 = blockIdx.x * 64, gn0 = blockIdx.y * 64;
    int kc = blockIdx.z;
    int kbase = kc * 352;
    int mi = tid >> 4, ni = tid & 15;
    int m0 = mi * 4, n0 = ni * 4;
    float acc[4][4] = {};

    for (int kt = 0; kt < 22; ++kt) {
        int k0 = kbase + kt*16;
        for (int idx = tid; idx < 1024; idx += 256) {
            int r = idx >> 4, c = idx & 15;
            As[c*68 + r] = feat[(size_t)(gm0 + r)*FEAT + k0 + c];
        }
        for (int idx = tid; idx < 1024; idx += 256) {
            int r = idx >> 6, c = idx & 63;
            Ws[r*68 + c] = wo[(size_t)(k0 + r)*OUTC + gn0 + c];
        }
        __syncthreads();
        #pragma unroll 8
        for (int kk = 0; kk < 16; ++kk) {
            float4 a = *(const float4*)&As[kk*68 + m0];
            float4 w = *(const float4*)&Ws[kk*68 + n0];
            acc[0][0] += a.x*w.x; acc[0][1] += a.x*w.y; acc[0][2] += a.x*w.z; acc[0][3] += a.x*w.w;
            acc[1][0] += a.y*w.x; acc[1][1] += a.y*w.y; acc[1][2] += a.y*w.z; acc[1][3] += a.y*w.w;
            acc[2][0] += a.z*w.x; acc[2][1] += a.z*w.y; acc[2][2] += a.z*w.z; acc[2][3] += a.z*w.w;
            acc[3][0] += a.w*w.x; acc[3][1] += a.w*w.y; acc[3][2] += a.w*w.z; acc[3][3] += a.w*w.w;
        }
        __syncthreads();
    }
    float* pb = pout + (size_t)kc * (NN*OUTC);
    #pragma unroll
    for (int i = 0; i < 4; ++i)
        *(float4*)&pb[(size_t)(gm0 + m0 + i)*OUTC + gn0 + n0] =
            make_float4(acc[i][0], acc[i][1], acc[i][2], acc[i][3]);
}

// ---------------- K4: reduce partials + bias ----------------
__global__ __launch_bounds__(256) void out_reduce(
    const float* __restrict__ pout, const float* __restrict__ bo,
    float* __restrict__ out)
{
    int idx4 = blockIdx.x * 256 + threadIdx.x;   // 49152 float4s
    int col4 = idx4 % 96;
    const float4* b4 = (const float4*)bo;
    float4 acc = b4[col4];
    #pragma unroll
    for (int kc = 0; kc < 6; ++kc) {
        float4 p = ((const float4*)(pout + (size_t)kc*(NN*OUTC)))[idx4];
        acc.x += p.x; acc.y += p.y; acc.z += p.z; acc.w += p.w;
    }
    ((float4*)out)[idx4] = acc;
}

extern "C" void kernel_launch(void* const* d_in, const int* in_sizes, int n_in,
                              void* d_out, int out_size, void* d_ws, size_t ws_size,
                              hipStream_t stream) {
    (void)in_sizes; (void)n_in; (void)out_size; (void)ws_size;
    const float* s     = (const float*)d_in[0];
    const float* z     = (const float*)d_in[1];
    const float* trans = (const float*)d_in[2];
    const float* rot   = (const float*)d_in[3];
    const int*   mask  = (const int*)d_in[4];
    const float* wq    = (const float*)d_in[5];
    const float* bq    = (const float*)d_in[6];
    const float* wk    = (const float*)d_in[7];
    const float* bk    = (const float*)d_in[8];
    const float* wv    = (const float*)d_in[9];
    const float* bv    = (const float*)d_in[10];
    const float* wqp   = (const float*)d_in[11];
    const float* bqp   = (const float*)d_in[12];
    const float* wkp   = (const float*)d_in[13];
    const float* bkp   = (const float*)d_in[14];
    const float* wvp   = (const float*)d_in[15];
    const float* bvp   = (const float*)d_in[16];
    const float* wb    = (const float*)d_in[17];
    const float* bb    = (const float*)d_in[18];
    const float* wo    = (const float*)d_in[19];
    const float* bo    = (const float*)d_in[20];
    float* ws  = (float*)d_ws;
    float* out = (float*)d_out;

    bias_gemm<<<4096, 256, 0, stream>>>(z, wb, bb, ws + WW);
    proj_gemm<<<dim3(8, 24), 256, 0, stream>>>(
        s, wq, bq, wk, bk, wv, bv, wqp, bqp, wkp, bkp, wvp, bvp, rot, trans,
        ws + WPROJ, ws + WKT);
    score_kernel<<<NN, 512, 0, stream>>>(ws + WPROJ, ws + WKT, ws + WW, mask, rot, trans, ws + WFEAT);
    pair_kernel<<<NN, 512, 0, stream>>>(ws + WW, z, ws + WFEAT);
    out_gemm<<<dim3(8, 6, 6), 256, 0, stream>>>(ws + WFEAT, wo, ws + WOUTP);
    out_reduce<<<192, 256, 0, stream>>>(ws + WOUTP, bo, out);
}

// Round 4
// 386.800 us; speedup vs baseline: 1.2282x; 1.1580x over previous
//
#include <hip/hip_runtime.h>

#define NN 512
#define CS 384
#define CZ 128
#define NH 12
#define PROJW 1152
#define FEAT 2112
#define OUTC 384
#define KC 12            // split-K chunks for out_gemm
#define KTILES 11        // K-tiles of 16 per chunk (12*11*16 = 2112)

// workspace float offsets
#define WPROJ 0          // [512][1152]: q 0:192 | k 192:384 | v 384:576 | qp 576:720 | kp 720:864 | vp 864:1152
#define WFEAT 589824     // [512][2112]
#define WW    1671168    // [512*512][12]: bias -> normalized w ; REUSED later as split-K pout
#define WOUTP 1671168    // [12][512][384] split-K partials (written after pair_kernel done reading WW)
#define WKT   4816896    // [336][512]: kT rows 0:192 = k cols, 192:336 = rotated kp cols

// ---------------- K1: proj GEMM (512x1152, K=384) + bias + fused point rotation + kT ----------------
__global__ __launch_bounds__(256) void proj_gemm(
    const float* __restrict__ s,
    const float* __restrict__ wq, const float* __restrict__ bq,
    const float* __restrict__ wk, const float* __restrict__ bk,
    const float* __restrict__ wv, const float* __restrict__ bv,
    const float* __restrict__ wqp, const float* __restrict__ bqp,
    const float* __restrict__ wkp, const float* __restrict__ bkp,
    const float* __restrict__ wvp, const float* __restrict__ bvp,
    const float* __restrict__ rot, const float* __restrict__ trans,
    float* __restrict__ proj, float* __restrict__ kT)
{
    __shared__ float As[32*68];
    __shared__ float Ws[32*52];
    int tid = threadIdx.x;
    int gm0 = blockIdx.x * 64;
    int gc0 = blockIdx.y * 48;
    const float *w, *b; int ldw, lc0;
    if      (gc0 < 192) { w = wq;  b = bq;  ldw = 192; lc0 = gc0;       }
    else if (gc0 < 384) { w = wk;  b = bk;  ldw = 192; lc0 = gc0 - 192; }
    else if (gc0 < 576) { w = wv;  b = bv;  ldw = 192; lc0 = gc0 - 384; }
    else if (gc0 < 720) { w = wqp; b = bqp; ldw = 144; lc0 = gc0 - 576; }
    else if (gc0 < 864) { w = wkp; b = bkp; ldw = 144; lc0 = gc0 - 720; }
    else                { w = wvp; b = bvp; ldw = 288; lc0 = gc0 - 864; }

    int mi = tid >> 4, ni = tid & 15;
    int m0 = mi * 4, n0 = ni * 3;
    float acc[4][3] = {};

    for (int k0 = 0; k0 < CS; k0 += 32) {
        for (int idx = tid; idx < 2048; idx += 256) {
            int r = idx >> 5, c = idx & 31;
            As[c*68 + r] = s[(gm0 + r)*CS + k0 + c];
        }
        for (int idx = tid; idx < 1536; idx += 256) {
            int c = idx / 48, j = idx - c*48;
            Ws[c*52 + j] = w[(k0 + c)*ldw + lc0 + j];
        }
        __syncthreads();
        #pragma unroll 8
        for (int kk = 0; kk < 32; ++kk) {
            float4 a = *(const float4*)&As[kk*68 + m0];
            float w0 = Ws[kk*52 + n0], w1 = Ws[kk*52 + n0 + 1], w2 = Ws[kk*52 + n0 + 2];
            acc[0][0] += a.x*w0; acc[0][1] += a.x*w1; acc[0][2] += a.x*w2;
            acc[1][0] += a.y*w0; acc[1][1] += a.y*w1; acc[1][2] += a.y*w2;
            acc[2][0] += a.z*w0; acc[2][1] += a.z*w1; acc[2][2] += a.z*w2;
            acc[3][0] += a.w*w0; acc[3][1] += a.w*w1; acc[3][2] += a.w*w2;
        }
        __syncthreads();
    }

    float b0 = b[lc0 + n0], b1 = b[lc0 + n0 + 1], b2 = b[lc0 + n0 + 2];
    if (gc0 >= 576) {
        #pragma unroll
        for (int i = 0; i < 4; ++i) {
            int gm = gm0 + m0 + i;
            const float* R = rot + gm*9;
            const float* T = trans + gm*3;
            float x = acc[i][0] + b0, y = acc[i][1] + b1, zz = acc[i][2] + b2;
            float gx = R[0]*x + R[1]*y + R[2]*zz + T[0];
            float gy = R[3]*x + R[4]*y + R[5]*zz + T[1];
            float gz = R[6]*x + R[7]*y + R[8]*zz + T[2];
            float* dst = proj + (size_t)gm*PROJW + gc0 + n0;
            dst[0] = gx; dst[1] = gy; dst[2] = gz;
            if (gc0 >= 720 && gc0 < 864) {        // rotated kp -> kT rows 192..335
                int c = 192 + (gc0 - 720) + n0;
                kT[(size_t)(c+0)*NN + gm] = gx;
                kT[(size_t)(c+1)*NN + gm] = gy;
                kT[(size_t)(c+2)*NN + gm] = gz;
            }
        }
    } else {
        #pragma unroll
        for (int i = 0; i < 4; ++i) {
            int gm = gm0 + m0 + i;
            float v0 = acc[i][0] + b0, v1 = acc[i][1] + b1, v2 = acc[i][2] + b2;
            float* dst = proj + (size_t)gm*PROJW + gc0 + n0;
            dst[0] = v0; dst[1] = v1; dst[2] = v2;
            if (gc0 >= 192 && gc0 < 384) {        // k -> kT rows 0..191
                int c = gc0 - 192 + n0;
                kT[(size_t)(c+0)*NN + gm] = v0;
                kT[(size_t)(c+1)*NN + gm] = v1;
                kT[(size_t)(c+2)*NN + gm] = v2;
            }
        }
    }
}

// ---------------- K2a: bias = z @ wb + bb  -> ww[nm][12]  (4096 blocks, HBM-bound) ----------------
__global__ __launch_bounds__(256) void bias_gemm(
    const float* __restrict__ z,
    const float* __restrict__ wb, const float* __restrict__ bb,
    float* __restrict__ ww)
{
    __shared__ float zl[64*128];     // XOR-swizzled float4 rows
    __shared__ float sb[64*12];
    int tid = threadIdx.x;
    size_t r0 = (size_t)blockIdx.x * 64;          // global nm row base

    const float4* src = (const float4*)(z + r0*CZ);
    float4 v[8];
    #pragma unroll
    for (int k = 0; k < 8; ++k) v[k] = src[tid + k*256];
    #pragma unroll
    for (int k = 0; k < 8; ++k) {
        int i = tid + k*256;
        int r = i >> 5, c4 = i & 31;
        *(float4*)&zl[r*128 + ((c4 ^ (r & 7)) << 2)] = v[k];
    }
    __syncthreads();

    int r = tid & 63, hg = tid >> 6;              // wave-uniform hg
    int h0 = __builtin_amdgcn_readfirstlane(hg * 3);
    const float* wbp = wb + h0;
    float a0 = bb[h0], a1 = bb[h0+1], a2 = bb[h0+2];
    #pragma unroll 8
    for (int c4 = 0; c4 < 32; ++c4) {
        float4 zv = *(const float4*)&zl[r*128 + ((c4 ^ (r & 7)) << 2)];
        int cb = c4*4;
        a0 += zv.x*wbp[cb*12]     + zv.y*wbp[(cb+1)*12]     + zv.z*wbp[(cb+2)*12]     + zv.w*wbp[(cb+3)*12];
        a1 += zv.x*wbp[cb*12 + 1] + zv.y*wbp[(cb+1)*12 + 1] + zv.z*wbp[(cb+2)*12 + 1] + zv.w*wbp[(cb+3)*12 + 1];
        a2 += zv.x*wbp[cb*12 + 2] + zv.y*wbp[(cb+1)*12 + 2] + zv.z*wbp[(cb+2)*12 + 2] + zv.w*wbp[(cb+3)*12 + 2];
    }
    float* sd = &sb[r*12 + h0];
    sd[0] = a0; sd[1] = a1; sd[2] = a2;
    __syncthreads();
    if (tid < 192) ((float4*)(ww + r0*12))[tid] = ((const float4*)sb)[tid];
}

// ---------------- K2b: scores (kT) + softmax + write w + v_out scalar/points/norms ----------------
__global__ __launch_bounds__(512, 4) void score_kernel(
    const float* __restrict__ proj, const float* __restrict__ kT,
    float* __restrict__ ww,                      // bias in, normalized w out
    const int* __restrict__ mask,
    const float* __restrict__ rot, const float* __restrict__ trans,
    float* __restrict__ feat)
{
    int n = blockIdx.x, tid = threadIdx.x;
    __shared__ float s_e[NN*12];     // bias -> scores -> exp -> w, [m][12]
    __shared__ float s_q[336];       // q (192) + rotated qp (144)
    __shared__ float s_pts[288];
    __shared__ float s_red[384];
    __shared__ float s_M[NH], s_S[NH];

    // load bias rows + q row
    {
        const float4* src = (const float4*)(ww + (size_t)n*NN*12);
        float4* dst = (float4*)s_e;
        #pragma unroll
        for (int k = 0; k < 3; ++k) dst[tid + k*512] = src[tid + k*512];
    }
    if (tid < 336) s_q[tid] = proj[(size_t)n*PROJW + (tid < 192 ? tid : 384 + tid)];
    int mn = mask[n];
    __syncthreads();

    // scores via transposed k/kp (lane-coalesced kT loads)
    {
        int m = tid;
        bool ok = (mn != 0) && (mask[m] != 0);
        float sc[12];
        #pragma unroll 2
        for (int h = 0; h < NH; ++h) {
            const float* qh  = &s_q[h*16];
            const float* kTh = kT + (size_t)(h*16)*NN + m;
            float dot = 0.f;
            #pragma unroll
            for (int cc = 0; cc < 16; ++cc) dot += qh[cc] * kTh[(size_t)cc*NN];
            const float* qph  = &s_q[192 + h*12];
            const float* kpTh = kT + (size_t)(192 + h*12)*NN + m;
            float pts = 0.f;
            #pragma unroll
            for (int j = 0; j < 12; ++j) { float d = qph[j] - kpTh[(size_t)j*NN]; pts += d*d; }
            sc[h] = dot*0.25f - 0.5f*pts;
        }
        float* row = &s_e[m*12];
        #pragma unroll
        for (int h = 0; h < NH; ++h) {
            float v = sc[h] + row[h];
            row[h] = ok ? v : -1e30f;
        }
    }
    __syncthreads();
    // max
    if (tid < 384) {
        int i = tid / 12, h = tid - i*12;
        float mx = -1e30f;
        for (int mm = i*16; mm < i*16 + 16; ++mm) mx = fmaxf(mx, s_e[mm*12 + h]);
        s_red[tid] = mx;
    }
    __syncthreads();
    if (tid < NH) {
        float mx = -1e30f;
        #pragma unroll
        for (int i = 0; i < 32; ++i) mx = fmaxf(mx, s_red[i*12 + tid]);
        s_M[tid] = mx;
    }
    __syncthreads();
    // exp in place
    {
        float M[12];
        #pragma unroll
        for (int h = 0; h < NH; ++h) M[h] = s_M[h];
        float* row = &s_e[tid*12];
        float4 a = *(float4*)row, b4 = *(float4*)(row+4), c4 = *(float4*)(row+8);
        a.x = __expf(a.x - M[0]);  a.y = __expf(a.y - M[1]);
        a.z = __expf(a.z - M[2]);  a.w = __expf(a.w - M[3]);
        b4.x = __expf(b4.x - M[4]); b4.y = __expf(b4.y - M[5]);
        b4.z = __expf(b4.z - M[6]); b4.w = __expf(b4.w - M[7]);
        c4.x = __expf(c4.x - M[8]); c4.y = __expf(c4.y - M[9]);
        c4.z = __expf(c4.z - M[10]); c4.w = __expf(c4.w - M[11]);
        *(float4*)row = a; *(float4*)(row+4) = b4; *(float4*)(row+8) = c4;
    }
    __syncthreads();
    // sum
    if (tid < 384) {
        int i = tid / 12, h = tid - i*12;
        float sm = 0.f;
        for (int mm = i*16; mm < i*16 + 16; ++mm) sm += s_e[mm*12 + h];
        s_red[tid] = sm;
    }
    __syncthreads();
    if (tid < NH) {
        float sm = 0.f;
        #pragma unroll
        for (int i = 0; i < 32; ++i) sm += s_red[i*12 + tid];
        s_S[tid] = sm;
    }
    __syncthreads();
    // normalize in place
    {
        float iS[12];
        #pragma unroll
        for (int h = 0; h < NH; ++h) iS[h] = 1.0f / s_S[h];
        float* row = &s_e[tid*12];
        float4 a = *(float4*)row, b4 = *(float4*)(row+4), c4 = *(float4*)(row+8);
        a.x *= iS[0]; a.y *= iS[1]; a.z *= iS[2]; a.w *= iS[3];
        b4.x *= iS[4]; b4.y *= iS[5]; b4.z *= iS[6]; b4.w *= iS[7];
        c4.x *= iS[8]; c4.y *= iS[9]; c4.z *= iS[10]; c4.w *= iS[11];
        *(float4*)row = a; *(float4*)(row+4) = b4; *(float4*)(row+8) = c4;
    }
    __syncthreads();
    // write normalized w back for pair_kernel
    {
        float4* dst = (float4*)(ww + (size_t)n*NN*12);
        const float4* src = (const float4*)s_e;
        #pragma unroll
        for (int k = 0; k < 3; ++k) dst[tid + k*512] = src[tid + k*512];
    }

    float* fout = feat + (size_t)n * FEAT;

    // v_out scalar (192) + points (288); plain loop, compiler-scheduled, 2 accumulators
    {
        int o = tid;
        if (o < 480) {
            int col, h; bool isPt = (o >= 192);
            if (!isPt) { col = 384 + o;       h = o >> 4; }
            else       { int p = o - 192; col = 864 + p; h = p / 24; }
            const float* pc = proj + col;
            float acc0 = 0.f, acc1 = 0.f;
            #pragma unroll 8
            for (int mm = 0; mm < NN; mm += 2) {
                acc0 += s_e[(mm  )*12 + h] * pc[(size_t)(mm  )*PROJW];
                acc1 += s_e[(mm+1)*12 + h] * pc[(size_t)(mm+1)*PROJW];
            }
            float acc = acc0 + acc1;
            if (!isPt) fout[h*176 + (o & 15)] = acc;
            else       s_pts[o - 192] = acc;
        }
    }
    __syncthreads();
    // local transform + norms
    if (tid < 96) {
        int h = tid >> 3, p = tid & 7;
        const float* R = rot + n*9;
        const float* T = trans + n*3;
        float x  = s_pts[h*24 + p*3]     - T[0];
        float y  = s_pts[h*24 + p*3 + 1] - T[1];
        float zz = s_pts[h*24 + p*3 + 2] - T[2];
        float lx = R[0]*x + R[3]*y + R[6]*zz;
        float ly = R[1]*x + R[4]*y + R[7]*zz;
        float lz = R[2]*x + R[5]*y + R[8]*zz;
        float* fo = fout + h*176 + 16;
        fo[p*3] = lx; fo[p*3+1] = ly; fo[p*3+2] = lz;
        fout[h*176 + 40 + p] = sqrtf(lx*lx + ly*ly + lz*lz);
    }
}

// ---------------- K2c: pair features = w . z  (per n, z re-read from L3) ----------------
__global__ __launch_bounds__(512, 4) void pair_kernel(
    const float* __restrict__ ww, const float* __restrict__ z,
    float* __restrict__ feat)
{
    int n = blockIdx.x, tid = threadIdx.x;
    __shared__ float s_w[NN*12];
    __shared__ float s_p[4*NH*128];
    {
        const float4* src = (const float4*)(ww + (size_t)n*NN*12);
        float4* dst = (float4*)s_w;
        #pragma unroll
        for (int k = 0; k < 3; ++k) dst[tid + k*512] = src[tid + k*512];
    }
    __syncthreads();
    int c = tid & 127, mh = tid >> 7;             // c column, m quarter
    const float* zb = z + ((size_t)n*NN + mh*128) * CZ + c;
    float pacc[12] = {};
    #pragma unroll 4
    for (int mm = 0; mm < 128; ++mm) {
        float zv = zb[(size_t)mm * CZ];
        const float* wr = &s_w[(mh*128 + mm)*12];           // broadcast across lanes
        float4 a = *(const float4*)wr, b4 = *(const float4*)(wr+4), c4 = *(const float4*)(wr+8);
        pacc[0] += a.x*zv;  pacc[1] += a.y*zv;  pacc[2] += a.z*zv;  pacc[3] += a.w*zv;
        pacc[4] += b4.x*zv; pacc[5] += b4.y*zv; pacc[6] += b4.z*zv; pacc[7] += b4.w*zv;
        pacc[8] += c4.x*zv; pacc[9] += c4.y*zv; pacc[10] += c4.z*zv; pacc[11] += c4.w*zv;
    }
    #pragma unroll
    for (int h = 0; h < NH; ++h) s_p[(mh*NH + h)*128 + c] = pacc[h];
    __syncthreads();
    {
        float* fout = feat + (size_t)n * FEAT;
        int cc = tid & 127, jh = tid >> 7;
        #pragma unroll
        for (int j = 0; j < 3; ++j) {
            int h = jh*3 + j;
            fout[h*176 + 48 + cc] = s_p[h*128 + cc] + s_p[(NH + h)*128 + cc]
                                  + s_p[(2*NH + h)*128 + cc] + s_p[(3*NH + h)*128 + cc];
        }
    }
}

// ---------------- K3: out GEMM split-K partials (512x384, K=2112, KC=12 x 176), reg-prefetch ----------------
__global__ __launch_bounds__(256) void out_gemm(
    const float* __restrict__ feat, const float* __restrict__ wo,
    float* __restrict__ pout)
{
    __shared__ float As[16*68];
    __shared__ float Ws[16*68];
    int tid = threadIdx.x;
    int gm0 = blockIdx.x * 64, gn0 = blockIdx.y * 64;
    int kc = blockIdx.z;
    int kbase = kc * (KTILES*16);
    int mi = tid >> 4, ni = tid & 15;
    int m0 = mi * 4, n0 = ni * 4;
    float acc[4][4] = {};

    // staging coords: feat rows ar+16k / col ac ; wo rows wr+4k / col wc
    int ar = tid >> 4, ac = tid & 15;
    int wr = tid >> 6, wc = tid & 63;

    float fa0, fa1, fa2, fa3, wa0, wa1, wa2, wa3;
    float fb0, fb1, fb2, fb3, wb0, wb1, wb2, wb3;
    {
        const float* fp = feat + (size_t)(gm0 + ar)*FEAT + kbase + ac;
        fa0 = fp[0]; fa1 = fp[16*FEAT]; fa2 = fp[32*FEAT]; fa3 = fp[48*FEAT];
        const float* wp = wo + (size_t)(kbase + wr)*OUTC + gn0 + wc;
        wa0 = wp[0]; wa1 = wp[4*OUTC]; wa2 = wp[8*OUTC]; wa3 = wp[12*OUTC];
    }
    for (int kt = 0; kt < KTILES; ++kt) {
        As[ac*68 + ar]      = fa0;
        As[ac*68 + ar + 16] = fa1;
        As[ac*68 + ar + 32] = fa2;
        As[ac*68 + ar + 48] = fa3;
        Ws[wr*68 + wc]        = wa0;
        Ws[(wr+4)*68 + wc]    = wa1;
        Ws[(wr+8)*68 + wc]    = wa2;
        Ws[(wr+12)*68 + wc]   = wa3;
        if (kt + 1 < KTILES) {
            int k0 = kbase + (kt+1)*16;
            const float* fp = feat + (size_t)(gm0 + ar)*FEAT + k0 + ac;
            fb0 = fp[0]; fb1 = fp[16*FEAT]; fb2 = fp[32*FEAT]; fb3 = fp[48*FEAT];
            const float* wp = wo + (size_t)(k0 + wr)*OUTC + gn0 + wc;
            wb0 = wp[0]; wb1 = wp[4*OUTC]; wb2 = wp[8*OUTC]; wb3 = wp[12*OUTC];
        }
        __syncthreads();
        #pragma unroll
        for (int kk = 0; kk < 16; ++kk) {
            float4 a = *(const float4*)&As[kk*68 + m0];
            float4 w = *(const float4*)&Ws[kk*68 + n0];
            acc[0][0] += a.x*w.x; acc[0][1] += a.x*w.y; acc[0][2] += a.x*w.z; acc[0][3] += a.x*w.w;
            acc[1][0] += a.y*w.x; acc[1][1] += a.y*w.y; acc[1][2] += a.y*w.z; acc[1][3] += a.y*w.w;
            acc[2][0] += a.z*w.x; acc[2][1] += a.z*w.y; acc[2][2] += a.z*w.z; acc[2][3] += a.z*w.w;
            acc[3][0] += a.w*w.x; acc[3][1] += a.w*w.y; acc[3][2] += a.w*w.z; acc[3][3] += a.w*w.w;
        }
        __syncthreads();
        fa0 = fb0; fa1 = fb1; fa2 = fb2; fa3 = fb3;
        wa0 = wb0; wa1 = wb1; wa2 = wb2; wa3 = wb3;
    }
    float* pb = pout + (size_t)kc * (NN*OUTC);
    #pragma unroll
    for (int i = 0; i < 4; ++i)
        *(float4*)&pb[(size_t)(gm0 + m0 + i)*OUTC + gn0 + n0] =
            make_float4(acc[i][0], acc[i][1], acc[i][2], acc[i][3]);
}

// ---------------- K4: reduce partials + bias ----------------
__global__ __launch_bounds__(256) void out_reduce(
    const float* __restrict__ pout, const float* __restrict__ bo,
    float* __restrict__ out)
{
    int idx4 = blockIdx.x * 256 + threadIdx.x;   // 49152 float4s
    int col4 = idx4 % 96;
    const float4* b4 = (const float4*)bo;
    float4 acc = b4[col4];
    #pragma unroll
    for (int kc = 0; kc < KC; ++kc) {
        float4 p = ((const float4*)(pout + (size_t)kc*(NN*OUTC)))[idx4];
        acc.x += p.x; acc.y += p.y; acc.z += p.z; acc.w += p.w;
    }
    ((float4*)out)[idx4] = acc;
}

extern "C" void kernel_launch(void* const* d_in, const int* in_sizes, int n_in,
                              void* d_out, int out_size, void* d_ws, size_t ws_size,
                              hipStream_t stream) {
    (void)in_sizes; (void)n_in; (void)out_size; (void)ws_size;
    const float* s     = (const float*)d_in[0];
    const float* z     = (const float*)d_in[1];
    const float* trans = (const float*)d_in[2];
    const float* rot   = (const float*)d_in[3];
    const int*   mask  = (const int*)d_in[4];
    const float* wq    = (const float*)d_in[5];
    const float* bq    = (const float*)d_in[6];
    const float* wk    = (const float*)d_in[7];
    const float* bk    = (const float*)d_in[8];
    const float* wv    = (const float*)d_in[9];
    const float* bv    = (const float*)d_in[10];
    const float* wqp   = (const float*)d_in[11];
    const float* bqp   = (const float*)d_in[12];
    const float* wkp   = (const float*)d_in[13];
    const float* bkp   = (const float*)d_in[14];
    const float* wvp   = (const float*)d_in[15];
    const float* bvp   = (const float*)d_in[16];
    const float* wb    = (const float*)d_in[17];
    const float* bb    = (const float*)d_in[18];
    const float* wo    = (const float*)d_in[19];
    const float* bo    = (const float*)d_in[20];
    float* ws  = (float*)d_ws;
    float* out = (float*)d_out;

    bias_gemm<<<4096, 256, 0, stream>>>(z, wb, bb, ws + WW);
    proj_gemm<<<dim3(8, 24), 256, 0, stream>>>(
        s, wq, bq, wk, bk, wv, bv, wqp, bqp, wkp, bkp, wvp, bvp, rot, trans,
        ws + WPROJ, ws + WKT);
    score_kernel<<<NN, 512, 0, stream>>>(ws + WPROJ, ws + WKT, ws + WW, mask, rot, trans, ws + WFEAT);
    pair_kernel<<<NN, 512, 0, stream>>>(ws + WW, z, ws + WFEAT);
    out_gemm<<<dim3(8, 6, KC), 256, 0, stream>>>(ws + WFEAT, wo, ws + WOUTP);
    out_reduce<<<192, 256, 0, stream>>>(ws + WOUTP, bo, out);
}